// Round 3
// baseline (409.281 us; speedup 1.0000x reference)
//
#include <hip/hip_runtime.h>

// Problem constants
#define B_   4
#define C_   256
#define N_   4096   // H*W
#define D_   32     // qk projection dim
#define CXP  130    // proj s_x paired-row stride (halves)

// flash LDS strides (halves) — chosen for 16B alignment + <=2-way banks
#define SVP2 40     // V row stride (32 data + 8 pad)
#define SPP2 36     // P row stride (32 data + 4 pad)
#define VWSZ (128*SVP2)   // per-wave V region: 5120 halves
#define PWSZ (32*SPP2)    // per-wave P region: 1152 halves

typedef _Float16 half8  __attribute__((ext_vector_type(8)));
typedef _Float16 half4t __attribute__((ext_vector_type(4)));
typedef _Float16 half2v __attribute__((ext_vector_type(2)));
typedef float    f32x4  __attribute__((ext_vector_type(4)));
typedef float    f32x16 __attribute__((ext_vector_type(16)));

union FragU { uint u[4]; half8 h; };

// ---------------------------------------------------------------------------
// Kernel 0: convert W (f32) -> Wh (f16) in MFMA-A-frag-friendly layout:
// Wh[((t*8+kc)*16 + row)*32 + kk] = W_t[row][kc*32+kk], t: 0-1 q, 2-3 k, 4-19 v
// ---------------------------------------------------------------------------
__global__ __launch_bounds__(256) void wcvt_kernel(
    const float* __restrict__ Wq, const float* __restrict__ Wk,
    const float* __restrict__ Wv, _Float16* __restrict__ Wh)
{
    const int idx = blockIdx.x * 256 + threadIdx.x;   // 0 .. 81920
    const int kk  = idx & 31;
    const int row = (idx >> 5) & 15;
    const int kc  = (idx >> 9) & 7;
    const int t   = idx >> 12;
    const int c   = kc*32 + kk;
    float v;
    if (t < 2)      v = Wq[(t*16 + row)*C_ + c];
    else if (t < 4) v = Wk[((t-2)*16 + row)*C_ + c];
    else            v = Wv[((t-4)*16 + row)*C_ + c];
    Wh[idx] = (_Float16)v;
}

// ---------------------------------------------------------------------------
// Kernel 1: projections (q = Wq@sem+bq, k = Wk@str+bk, v = Wv@str+bv).
// A = Wh f16 (global b128 frags), B = X staged via LDS transpose (paired b32).
// Outputs: Qh,Kh (B, 4 dchunk, N, 8) f16;  Vh (B, C, N) f16.
// ---------------------------------------------------------------------------
__global__ __launch_bounds__(256, 2) void proj_kernel(
    const float* __restrict__ sem, const float* __restrict__ str,
    const _Float16* __restrict__ Wh,
    const float* __restrict__ bq, const float* __restrict__ bk,
    const float* __restrict__ bv,
    _Float16* __restrict__ Qh, _Float16* __restrict__ Kh, _Float16* __restrict__ Vh)
{
    __shared__ _Float16 s_xt[16 * CXP];
    __shared__ _Float16 s_xs[16 * CXP];

    const int bid = blockIdx.x;
    const int h   = bid & 1;
    const int nt6 = (bid >> 1) & 63;
    const int b   = bid >> 7;
    const int n0  = nt6 * 64;
    const int tid = threadIdx.x;
    const int w    = tid >> 6;
    const int lane = tid & 63;
    const int quad = lane >> 4;
    const int l15  = lane & 15;

    const int cnt = (w < 2) ? 3 : 2;
    const int t0  = h*10 + ((w < 2) ? w*3 : 6 + (w-2)*2);
    const bool need_sem = (h == 0);

    f32x4 acc[3][4];
    #pragma unroll
    for (int i = 0; i < 3; ++i)
        #pragma unroll
        for (int j = 0; j < 4; ++j) { acc[i][j][0]=0.f; acc[i][j][1]=0.f; acc[i][j][2]=0.f; acc[i][j][3]=0.f; }

    const int sc = tid >> 4;        // c-pair 0..15
    const int sn = (tid & 15) * 4;  // n offset 0..60
    const size_t xbase = (size_t)b * C_ * N_;

    float4 xt0 = *(const float4*)(str + xbase + (size_t)(2*sc)     * N_ + n0 + sn);
    float4 xt1 = *(const float4*)(str + xbase + (size_t)(2*sc + 1) * N_ + n0 + sn);
    float4 xs0, xs1;
    if (need_sem) {
        xs0 = *(const float4*)(sem + xbase + (size_t)(2*sc)     * N_ + n0 + sn);
        xs1 = *(const float4*)(sem + xbase + (size_t)(2*sc + 1) * N_ + n0 + sn);
    }

    #pragma unroll 1
    for (int kc = 0; kc < 8; ++kc) {
        __syncthreads();
        #pragma unroll
        for (int t = 0; t < 4; ++t) {
            half2v hp; hp[0] = (_Float16)xt0[t]; hp[1] = (_Float16)xt1[t];
            *(half2v*)(s_xt + sc*CXP + (sn + t)*2) = hp;
        }
        if (need_sem) {
            #pragma unroll
            for (int t = 0; t < 4; ++t) {
                half2v hp; hp[0] = (_Float16)xs0[t]; hp[1] = (_Float16)xs1[t];
                *(half2v*)(s_xs + sc*CXP + (sn + t)*2) = hp;
            }
        }
        __syncthreads();
        if (kc < 7) {
            xt0 = *(const float4*)(str + xbase + (size_t)((kc+1)*32 + 2*sc)     * N_ + n0 + sn);
            xt1 = *(const float4*)(str + xbase + (size_t)((kc+1)*32 + 2*sc + 1) * N_ + n0 + sn);
            if (need_sem) {
                xs0 = *(const float4*)(sem + xbase + (size_t)((kc+1)*32 + 2*sc)     * N_ + n0 + sn);
                xs1 = *(const float4*)(sem + xbase + (size_t)((kc+1)*32 + 2*sc + 1) * N_ + n0 + sn);
            }
        }

        half8 bt[4], bs_[4];
        #pragma unroll
        for (int nt = 0; nt < 4; ++nt) {
            FragU fu;
            #pragma unroll
            for (int v = 0; v < 4; ++v)
                fu.u[v] = *(const uint*)(s_xt + (quad*4 + v)*CXP + (nt*16 + l15)*2);
            bt[nt] = fu.h;
        }
        if (w == 0 && h == 0) {
            #pragma unroll
            for (int nt = 0; nt < 4; ++nt) {
                FragU fu;
                #pragma unroll
                for (int v = 0; v < 4; ++v)
                    fu.u[v] = *(const uint*)(s_xs + (quad*4 + v)*CXP + (nt*16 + l15)*2);
                bs_[nt] = fu.h;
            }
        }

        #pragma unroll
        for (int mi = 0; mi < 3; ++mi) {
            if (mi >= cnt) break;
            const int t = t0 + mi;
            half8 af = *(const half8*)(Wh + ((size_t)((t*8 + kc)*16 + l15))*32 + quad*8);
            #pragma unroll
            for (int nt = 0; nt < 4; ++nt)
                acc[mi][nt] = __builtin_amdgcn_mfma_f32_16x16x32_f16(
                                  af, (t < 2) ? bs_[nt] : bt[nt], acc[mi][nt], 0, 0, 0);
        }
    }

    // Epilogue: bias, f16 convert, store
    #pragma unroll
    for (int mi = 0; mi < 3; ++mi) {
        if (mi >= cnt) break;
        const int t = t0 + mi;
        if (t < 4) {
            const bool isq = (t < 2);
            const int  tt  = isq ? t : (t - 2);
            f32x4 b4 = *(const f32x4*)((isq ? bq : bk) + tt*16 + quad*4);
            _Float16* dst = isq ? Qh : Kh;
            const int dc  = tt*2 + (quad >> 1);
            const int off = (quad & 1) * 4;
            #pragma unroll
            for (int nt = 0; nt < 4; ++nt) {
                const int n = n0 + nt*16 + l15;
                f32x4 a = acc[mi][nt];
                half4t hq;
                hq[0]=(_Float16)(a[0]+b4[0]); hq[1]=(_Float16)(a[1]+b4[1]);
                hq[2]=(_Float16)(a[2]+b4[2]); hq[3]=(_Float16)(a[3]+b4[3]);
                *(half4t*)(dst + ((size_t)(b*4 + dc) * N_ + n) * 8 + off) = hq;
            }
        } else {
            const int o0 = (t-4)*16 + quad*4;
            f32x4 b4 = *(const f32x4*)(bv + o0);
            #pragma unroll
            for (int nt = 0; nt < 4; ++nt) {
                const int n = n0 + nt*16 + l15;
                f32x4 a = acc[mi][nt];
                _Float16* vv = Vh + ((size_t)(b*C_) + o0) * (size_t)N_ + n;
                vv[0]            = (_Float16)(a[0]+b4[0]);
                vv[(size_t)N_]   = (_Float16)(a[1]+b4[1]);
                vv[(size_t)2*N_] = (_Float16)(a[2]+b4[2]);
                vv[(size_t)3*N_] = (_Float16)(a[3]+b4[3]);
            }
        }
    }
}

// ---------------------------------------------------------------------------
// Kernel 2: flash attention, fixed-max two-phase, barrier-free main loop.
// Block = 512 thr = 8 waves, covers 32 q-rows. Wave w: ch = w>>2 (c-half 128),
// jq = w&3 (j-quarter 1024). Phase 0: exact row max (waves split j 8-way,
// one barrier). Main loop (32 iters, TJ=32): wave-private V tile staged to
// its own LDS region (no barriers), S^T via 16x16 MFMA with K frags loaded
// straight from global, P through private LDS, PV via 32x32x16 MFMA.
// End: LDS tree-combine of O over jq + l, fused gamma*O/l + semantic store.
// ---------------------------------------------------------------------------
__global__ __launch_bounds__(512, 2) void flash_kernel(
    const _Float16* __restrict__ Qh, const _Float16* __restrict__ Kh,
    const _Float16* __restrict__ Vh, const float* __restrict__ sem,
    const float* __restrict__ gma, float* __restrict__ out)
{
    __shared__ __align__(16) _Float16 s_v[8 * VWSZ];   // 80 KB (overlaid by O-combine)
    __shared__ __align__(16) _Float16 s_p[8 * PWSZ];   // 18 KB
    __shared__ float s_mp[8*32];
    __shared__ float s_lp[8*32];

    const int bid = blockIdx.x;
    const int b   = bid >> 7;
    const int i0  = (bid & 127) * 32;
    const int tid = threadIdx.x;
    const int w    = tid >> 6;
    const int lane = tid & 63;
    const int quad = lane >> 4;
    const int l15  = lane & 15;
    const int l31  = lane & 31;
    const int hw   = lane >> 5;
    const int ch   = w >> 2;
    const int jq   = w & 3;
    const int jbase = jq * 1024;

    // Q B-frags (B[k=d][n=i], d-chunk = quad), i = i0 + ih*16 + l15
    const _Float16* qchunk = Qh + (size_t)(b*4 + quad) * N_ * 8;
    half8 qf0 = *(const half8*)(qchunk + (size_t)(i0 + l15) * 8);
    half8 qf1 = *(const half8*)(qchunk + (size_t)(i0 + 16 + l15) * 8);

    const _Float16* kchunk = Kh + (size_t)(b*4 + quad) * N_ * 8;

    // V staging pointers (wave-private): lane handles rows (lane>>2)+16r, part lane&3
    const _Float16* vptr = Vh + ((size_t)(b*C_ + ch*128 + (lane>>2))) * N_ + jbase + (lane&3)*8;
    _Float16* svw = s_v + w*VWSZ + (lane>>2)*SVP2 + (lane&3)*8;
    _Float16* spw = s_p + w*PWSZ;

    // preload first V tile (in flight during phase 0)
    uint4 vreg[8];
    #pragma unroll
    for (int r = 0; r < 8; ++r)
        vreg[r] = *(const uint4*)(vptr + (size_t)r*16*N_);

    // ---- phase 0: exact row max over this wave's 512-j slice ----
    float mx0 = -3e38f, mx1 = -3e38f;
    #pragma unroll 1
    for (int it = 0; it < 8; ++it) {
        const int j0 = w*512 + it*64;
        #pragma unroll
        for (int jt = 0; jt < 4; ++jt) {
            half8 kf = *(const half8*)(kchunk + (size_t)(j0 + jt*16 + l15) * 8);
            f32x4 z; z[0]=0.f; z[1]=0.f; z[2]=0.f; z[3]=0.f;
            f32x4 s0 = __builtin_amdgcn_mfma_f32_16x16x32_f16(kf, qf0, z, 0, 0, 0);
            f32x4 s1 = __builtin_amdgcn_mfma_f32_16x16x32_f16(kf, qf1, z, 0, 0, 0);
            #pragma unroll
            for (int r = 0; r < 4; ++r) { mx0 = fmaxf(mx0, s0[r]); mx1 = fmaxf(mx1, s1[r]); }
        }
    }
    mx0 = fmaxf(mx0, __shfl_xor(mx0, 16)); mx0 = fmaxf(mx0, __shfl_xor(mx0, 32));
    mx1 = fmaxf(mx1, __shfl_xor(mx1, 16)); mx1 = fmaxf(mx1, __shfl_xor(mx1, 32));
    if (lane < 32) s_mp[w*32 + lane] = (lane < 16) ? mx0 : mx1;
    __syncthreads();
    float mf0 = -3e38f, mf1 = -3e38f;
    #pragma unroll
    for (int ww = 0; ww < 8; ++ww) {
        mf0 = fmaxf(mf0, s_mp[ww*32 + l15]);
        mf1 = fmaxf(mf1, s_mp[ww*32 + 16 + l15]);
    }

    // ---- main loop: barrier-free ----
    f32x16 acc[4];
    #pragma unroll
    for (int ct = 0; ct < 4; ++ct)
        #pragma unroll
        for (int e = 0; e < 16; ++e) acc[ct][e] = 0.f;
    float lp0 = 0.f, lp1 = 0.f;

    half8 kreg0 = *(const half8*)(kchunk + (size_t)(jbase + l15) * 8);
    half8 kreg1 = *(const half8*)(kchunk + (size_t)(jbase + 16 + l15) * 8);

    #pragma unroll 1
    for (int itn = 0; itn < 32; ++itn) {
        // stage this iter's V tile (wave-private region)
        #pragma unroll
        for (int r = 0; r < 8; ++r)
            *(uint4*)(svw + r*16*SVP2) = vreg[r];

        // S^T = K Q (D[m=j][n=i]): 2 j-tiles x 2 i-halves
        f32x4 z; z[0]=0.f; z[1]=0.f; z[2]=0.f; z[3]=0.f;
        f32x4 sf00 = __builtin_amdgcn_mfma_f32_16x16x32_f16(kreg0, qf0, z, 0, 0, 0);
        f32x4 sf01 = __builtin_amdgcn_mfma_f32_16x16x32_f16(kreg0, qf1, z, 0, 0, 0);
        f32x4 sf10 = __builtin_amdgcn_mfma_f32_16x16x32_f16(kreg1, qf0, z, 0, 0, 0);
        f32x4 sf11 = __builtin_amdgcn_mfma_f32_16x16x32_f16(kreg1, qf1, z, 0, 0, 0);

        // prefetch next iter's K frags and V tile
        if (itn < 31) {
            const int jn = jbase + (itn+1)*32;
            kreg0 = *(const half8*)(kchunk + (size_t)(jn + l15) * 8);
            kreg1 = *(const half8*)(kchunk + (size_t)(jn + 16 + l15) * 8);
            #pragma unroll
            for (int r = 0; r < 8; ++r)
                vreg[r] = *(const uint4*)(vptr + (size_t)r*16*N_ + (itn+1)*32);
        }

        // softmax with fixed max; write P [i][j] to private LDS
        _Float16* pb = spw + l15*SPP2 + quad*4;
        {
            float e0=__expf(sf00[0]-mf0), e1=__expf(sf00[1]-mf0), e2=__expf(sf00[2]-mf0), e3=__expf(sf00[3]-mf0);
            lp0 += (e0+e1)+(e2+e3);
            half4t hp; hp[0]=(_Float16)e0; hp[1]=(_Float16)e1; hp[2]=(_Float16)e2; hp[3]=(_Float16)e3;
            *(half4t*)(pb) = hp;
        }
        {
            float e0=__expf(sf10[0]-mf0), e1=__expf(sf10[1]-mf0), e2=__expf(sf10[2]-mf0), e3=__expf(sf10[3]-mf0);
            lp0 += (e0+e1)+(e2+e3);
            half4t hp; hp[0]=(_Float16)e0; hp[1]=(_Float16)e1; hp[2]=(_Float16)e2; hp[3]=(_Float16)e3;
            *(half4t*)(pb + 16) = hp;
        }
        {
            float e0=__expf(sf01[0]-mf1), e1=__expf(sf01[1]-mf1), e2=__expf(sf01[2]-mf1), e3=__expf(sf01[3]-mf1);
            lp1 += (e0+e1)+(e2+e3);
            half4t hp; hp[0]=(_Float16)e0; hp[1]=(_Float16)e1; hp[2]=(_Float16)e2; hp[3]=(_Float16)e3;
            *(half4t*)(pb + 16*SPP2) = hp;
        }
        {
            float e0=__expf(sf11[0]-mf1), e1=__expf(sf11[1]-mf1), e2=__expf(sf11[2]-mf1), e3=__expf(sf11[3]-mf1);
            lp1 += (e0+e1)+(e2+e3);
            half4t hp; hp[0]=(_Float16)e0; hp[1]=(_Float16)e1; hp[2]=(_Float16)e2; hp[3]=(_Float16)e3;
            *(half4t*)(pb + 16*SPP2 + 16) = hp;
        }

        // O[c][i] += V P  (32x32x16; A = V rows c, B = P rows i)
        #pragma unroll
        for (int s = 0; s < 2; ++s) {
            half8 pf = *(const half8*)(spw + l31*SPP2 + s*16 + hw*8);
            #pragma unroll
            for (int ct = 0; ct < 4; ++ct) {
                half8 vf = *(const half8*)(s_v + w*VWSZ + (ct*32 + l31)*SVP2 + s*16 + hw*8);
                acc[ct] = __builtin_amdgcn_mfma_f32_32x32x16_f16(vf, pf, acc[ct], 0, 0, 0);
            }
        }
    }

    // ---- combine across jq (and l), fused epilogue ----
    lp0 += __shfl_xor(lp0, 16); lp0 += __shfl_xor(lp0, 32);
    lp1 += __shfl_xor(lp1, 16); lp1 += __shfl_xor(lp1, 32);

    __syncthreads();                               // B1: all PV LDS reads done
    if (lane < 32) s_lp[w*32 + lane] = (lane < 16) ? lp0 : lp1;
    float* s_acc = (float*)s_v;                    // overlay: 4 slots x 16 KB

    if (jq >= 2) {                                 // round-1 donors
        const int slot = ch*2 + (jq - 2);
        #pragma unroll
        for (int ct = 0; ct < 4; ++ct)
            #pragma unroll
            for (int p4 = 0; p4 < 4; ++p4) {
                f32x4 t; t[0]=acc[ct][p4*4]; t[1]=acc[ct][p4*4+1]; t[2]=acc[ct][p4*4+2]; t[3]=acc[ct][p4*4+3];
                *(f32x4*)(s_acc + slot*4096 + (ct*4 + p4)*256 + lane*4) = t;
            }
    }
    __syncthreads();                               // B2
    if (jq < 2) {                                  // round-1 receivers
        const int slot = ch*2 + jq;
        #pragma unroll
        for (int ct = 0; ct < 4; ++ct)
            #pragma unroll
            for (int p4 = 0; p4 < 4; ++p4) {
                f32x4 t = *(const f32x4*)(s_acc + slot*4096 + (ct*4 + p4)*256 + lane*4);
                acc[ct][p4*4]   += t[0]; acc[ct][p4*4+1] += t[1];
                acc[ct][p4*4+2] += t[2]; acc[ct][p4*4+3] += t[3];
            }
        if (jq == 1) {                             // round-2 donor (reuse own slot)
            const int slot2 = ch*2 + 1;
            #pragma unroll
            for (int ct = 0; ct < 4; ++ct)
                #pragma unroll
                for (int p4 = 0; p4 < 4; ++p4) {
                    f32x4 t; t[0]=acc[ct][p4*4]; t[1]=acc[ct][p4*4+1]; t[2]=acc[ct][p4*4+2]; t[3]=acc[ct][p4*4+3];
                    *(f32x4*)(s_acc + slot2*4096 + (ct*4 + p4)*256 + lane*4) = t;
                }
        }
    }
    __syncthreads();                               // B3
    if (jq == 0) {
        const int slot2 = ch*2 + 1;
        #pragma unroll
        for (int ct = 0; ct < 4; ++ct)
            #pragma unroll
            for (int p4 = 0; p4 < 4; ++p4) {
                f32x4 t = *(const f32x4*)(s_acc + slot2*4096 + (ct*4 + p4)*256 + lane*4);
                acc[ct][p4*4]   += t[0]; acc[ct][p4*4+1] += t[1];
                acc[ct][p4*4+2] += t[2]; acc[ct][p4*4+3] += t[3];
            }
        // l (sum over the 4 jq of ch==0's waves — identical S on both ch)
        const float li = s_lp[l31] + s_lp[32 + l31] + s_lp[64 + l31] + s_lp[96 + l31];
        const float g  = gma[0];
        const float sc = g / li;
        #pragma unroll
        for (int ct = 0; ct < 4; ++ct)
            #pragma unroll
            for (int r = 0; r < 16; ++r) {
                const int c = ch*128 + ct*32 + (r & 3) + 8*(r >> 2) + 4*hw;
                const size_t idx = ((size_t)(b*C_ + c)) * N_ + i0 + l31;
                out[idx] = acc[ct][r] * sc + sem[idx];
            }
    }
}

extern "C" void kernel_launch(void* const* d_in, const int* in_sizes, int n_in,
                              void* d_out, int out_size, void* d_ws, size_t ws_size,
                              hipStream_t stream) {
    const float* sem = (const float*)d_in[0];
    const float* str = (const float*)d_in[1];
    const float* Wq  = (const float*)d_in[2];
    const float* bq  = (const float*)d_in[3];
    const float* Wk  = (const float*)d_in[4];
    const float* bk  = (const float*)d_in[5];
    const float* Wv  = (const float*)d_in[6];
    const float* bv  = (const float*)d_in[7];
    const float* gma = (const float*)d_in[8];
    float* out = (float*)d_out;

    // Workspace (f16): Qh 1MB | Kh 1MB | Vh 8MB | Wh 160KB
    _Float16* Qh = (_Float16*)d_ws;
    _Float16* Kh = Qh + (size_t)B_*N_*D_;
    _Float16* Vh = Kh + (size_t)B_*N_*D_;
    _Float16* Wh = Vh + (size_t)B_*C_*N_;

    hipLaunchKernelGGL(wcvt_kernel, dim3(320), dim3(256), 0, stream, Wq, Wk, Wv, Wh);
    hipLaunchKernelGGL(proj_kernel, dim3(B_*(N_/64)*2), dim3(256), 0, stream,
                       sem, str, Wh, bq, bk, bv, Qh, Kh, Vh);
    hipLaunchKernelGGL(flash_kernel, dim3(B_*(N_/32)), dim3(512), 0, stream,
                       Qh, Kh, Vh, sem, gma, out);
}

// Round 4
// 207.127 us; speedup vs baseline: 1.9760x; 1.9760x over previous
//
#include <hip/hip_runtime.h>

// Problem constants
#define B_   4
#define C_   256
#define N_   4096   // H*W
#define D_   32     // qk projection dim
#define CXP  130    // proj s_x paired-row stride (halves)

typedef _Float16 half8  __attribute__((ext_vector_type(8)));
typedef _Float16 half4v __attribute__((ext_vector_type(4)));
typedef _Float16 half2v __attribute__((ext_vector_type(2)));
typedef float    f32x4  __attribute__((ext_vector_type(4)));

union FragU { uint u[4]; half8 h; };

// ---------------------------------------------------------------------------
// Kernel 0: convert W (f32) -> Wh (f16), A-frag layout:
// Wh[((t*8+kc)*16 + row)*32 + kk] = W_t[row][kc*32+kk], t: 0-1 q, 2-3 k, 4-19 v
// ---------------------------------------------------------------------------
__global__ __launch_bounds__(256) void wcvt_kernel(
    const float* __restrict__ Wq, const float* __restrict__ Wk,
    const float* __restrict__ Wv, _Float16* __restrict__ Wh)
{
    const int idx = blockIdx.x * 256 + threadIdx.x;
    const int kk  = idx & 31;
    const int row = (idx >> 5) & 15;
    const int kc  = (idx >> 9) & 7;
    const int t   = idx >> 12;
    const int c   = kc*32 + kk;
    float v;
    if (t < 2)      v = Wq[(t*16 + row)*C_ + c];
    else if (t < 4) v = Wk[((t-2)*16 + row)*C_ + c];
    else            v = Wv[((t-4)*16 + row)*C_ + c];
    Wh[idx] = (_Float16)v;
}

// ---------------------------------------------------------------------------
// Kernel 1: projections (q = Wq@sem+bq, k = Wk@str+bk, v = Wv@str+bv).
// Same structure as R2 (proven correct). Only change: V is stored in
// frag-major layout Vh2 for the flash kernel's direct-from-global A-frags:
//   Vh2[b][jc=j/16][ct=c/16][lane][e] , lane = (jl/4)*16 + cl, e = jl&3
// Qh,Kh stay (B, 4 dchunk, N, 8) f16.
// ---------------------------------------------------------------------------
__global__ __launch_bounds__(256, 2) void proj_kernel(
    const float* __restrict__ sem, const float* __restrict__ str,
    const _Float16* __restrict__ Wh,
    const float* __restrict__ bq, const float* __restrict__ bk,
    const float* __restrict__ bv,
    _Float16* __restrict__ Qh, _Float16* __restrict__ Kh, _Float16* __restrict__ Vh2)
{
    __shared__ _Float16 s_xt[16 * CXP];
    __shared__ _Float16 s_xs[16 * CXP];

    const int bid = blockIdx.x;
    const int h   = bid & 1;
    const int nt6 = (bid >> 1) & 63;
    const int b   = bid >> 7;
    const int n0  = nt6 * 64;
    const int tid = threadIdx.x;
    const int w    = tid >> 6;
    const int lane = tid & 63;
    const int quad = lane >> 4;
    const int l15  = lane & 15;

    const int cnt = (w < 2) ? 3 : 2;
    const int t0  = h*10 + ((w < 2) ? w*3 : 6 + (w-2)*2);
    const bool need_sem = (h == 0);

    f32x4 acc[3][4];
    #pragma unroll
    for (int i = 0; i < 3; ++i)
        #pragma unroll
        for (int j = 0; j < 4; ++j) { acc[i][j][0]=0.f; acc[i][j][1]=0.f; acc[i][j][2]=0.f; acc[i][j][3]=0.f; }

    const int sc = tid >> 4;
    const int sn = (tid & 15) * 4;
    const size_t xbase = (size_t)b * C_ * N_;

    float4 xt0 = *(const float4*)(str + xbase + (size_t)(2*sc)     * N_ + n0 + sn);
    float4 xt1 = *(const float4*)(str + xbase + (size_t)(2*sc + 1) * N_ + n0 + sn);
    float4 xs0, xs1;
    if (need_sem) {
        xs0 = *(const float4*)(sem + xbase + (size_t)(2*sc)     * N_ + n0 + sn);
        xs1 = *(const float4*)(sem + xbase + (size_t)(2*sc + 1) * N_ + n0 + sn);
    }

    #pragma unroll 1
    for (int kc = 0; kc < 8; ++kc) {
        __syncthreads();
        #pragma unroll
        for (int t = 0; t < 4; ++t) {
            half2v hp; hp[0] = (_Float16)xt0[t]; hp[1] = (_Float16)xt1[t];
            *(half2v*)(s_xt + sc*CXP + (sn + t)*2) = hp;
        }
        if (need_sem) {
            #pragma unroll
            for (int t = 0; t < 4; ++t) {
                half2v hp; hp[0] = (_Float16)xs0[t]; hp[1] = (_Float16)xs1[t];
                *(half2v*)(s_xs + sc*CXP + (sn + t)*2) = hp;
            }
        }
        __syncthreads();
        if (kc < 7) {
            xt0 = *(const float4*)(str + xbase + (size_t)((kc+1)*32 + 2*sc)     * N_ + n0 + sn);
            xt1 = *(const float4*)(str + xbase + (size_t)((kc+1)*32 + 2*sc + 1) * N_ + n0 + sn);
            if (need_sem) {
                xs0 = *(const float4*)(sem + xbase + (size_t)((kc+1)*32 + 2*sc)     * N_ + n0 + sn);
                xs1 = *(const float4*)(sem + xbase + (size_t)((kc+1)*32 + 2*sc + 1) * N_ + n0 + sn);
            }
        }

        half8 bt[4], bs_[4];
        #pragma unroll
        for (int nt = 0; nt < 4; ++nt) {
            FragU fu;
            #pragma unroll
            for (int v = 0; v < 4; ++v)
                fu.u[v] = *(const uint*)(s_xt + (quad*4 + v)*CXP + (nt*16 + l15)*2);
            bt[nt] = fu.h;
        }
        if (w == 0 && h == 0) {
            #pragma unroll
            for (int nt = 0; nt < 4; ++nt) {
                FragU fu;
                #pragma unroll
                for (int v = 0; v < 4; ++v)
                    fu.u[v] = *(const uint*)(s_xs + (quad*4 + v)*CXP + (nt*16 + l15)*2);
                bs_[nt] = fu.h;
            }
        }

        #pragma unroll
        for (int mi = 0; mi < 3; ++mi) {
            if (mi >= cnt) break;
            const int t = t0 + mi;
            half8 af = *(const half8*)(Wh + ((size_t)((t*8 + kc)*16 + l15))*32 + quad*8);
            #pragma unroll
            for (int nt = 0; nt < 4; ++nt)
                acc[mi][nt] = __builtin_amdgcn_mfma_f32_16x16x32_f16(
                                  af, (t < 2) ? bs_[nt] : bt[nt], acc[mi][nt], 0, 0, 0);
        }
    }

    // Epilogue: bias, f16 convert, store
    #pragma unroll
    for (int mi = 0; mi < 3; ++mi) {
        if (mi >= cnt) break;
        const int t = t0 + mi;
        if (t < 4) {
            const bool isq = (t < 2);
            const int  tt  = isq ? t : (t - 2);
            f32x4 b4 = *(const f32x4*)((isq ? bq : bk) + tt*16 + quad*4);
            _Float16* dst = isq ? Qh : Kh;
            const int dc  = tt*2 + (quad >> 1);
            const int off = (quad & 1) * 4;
            #pragma unroll
            for (int nt = 0; nt < 4; ++nt) {
                const int n = n0 + nt*16 + l15;
                f32x4 a = acc[mi][nt];
                half4v hq;
                hq[0]=(_Float16)(a[0]+b4[0]); hq[1]=(_Float16)(a[1]+b4[1]);
                hq[2]=(_Float16)(a[2]+b4[2]); hq[3]=(_Float16)(a[3]+b4[3]);
                *(half4v*)(dst + ((size_t)(b*4 + dc) * N_ + n) * 8 + off) = hq;
            }
        } else {
            const int ct = t - 4;
            const int o0 = ct*16 + quad*4;
            f32x4 b4 = *(const f32x4*)(bv + o0);
            // Vh2 frag-major store: jc = n/16, cl = quad*4+r, jl = l15
            _Float16* vb = Vh2 + (size_t)b * (size_t)N_ * C_;
            #pragma unroll
            for (int nt = 0; nt < 4; ++nt) {
                const int jc = (n0 >> 4) + nt;
                const size_t fragb = ((size_t)jc * 16 + ct) * 256;  // 64 lanes * 4 halves
                const int lp = (l15 >> 2) * 16;    // lane' high part from j-local
                const int e  = l15 & 3;
                f32x4 a = acc[mi][nt];
                #pragma unroll
                for (int r = 0; r < 4; ++r)
                    vb[fragb + (size_t)(lp + quad*4 + r)*4 + e] = (_Float16)(a[r] + b4[r]);
            }
        }
    }
}

// ---------------------------------------------------------------------------
// Kernel 2: flash attention v4 — zero-LDS, barrier-free, register-resident P.
// 2048 independent waves: wave = (b, 32-row i-tile, 64-ch c-slice).
// S^T via 16x16x32 (K A-frags, Q B-frags from global); S^T's C-layout equals
// the 16x16x16 B-operand layout, so P feeds PV mfma straight from registers.
// V A-frags (half4) load coalesced from frag-major Vh2. K/V double-buffered
// in registers one 64-j tile ahead. Online softmax per-lane (2 shuffles/row).
// ---------------------------------------------------------------------------
__global__ __launch_bounds__(256, 2) void flash_kernel(
    const _Float16* __restrict__ Qh, const _Float16* __restrict__ Kh,
    const _Float16* __restrict__ Vh2, const float* __restrict__ sem,
    const float* __restrict__ gma, float* __restrict__ out)
{
    const int bid = blockIdx.x;
    const int b   = bid >> 7;
    const int i0  = (bid & 127) * 32;
    const int tid = threadIdx.x;
    const int w    = tid >> 6;
    const int lane = tid & 63;
    const int quad = lane >> 4;
    const int l15  = lane & 15;
    const int c0   = w * 64;
    const int w4   = w * 4;     // c-tile base

    // Q B-frags (persistent): B[k=d][n=i]
    const _Float16* qk_base = Qh + (size_t)(b*4 + quad) * N_ * 8;
    const half8 qf0 = *(const half8*)(qk_base + (size_t)(i0 + l15) * 8);
    const half8 qf1 = *(const half8*)(qk_base + (size_t)(i0 + 16 + l15) * 8);

    const _Float16* klane = Kh + ((size_t)(b*4 + quad) * N_ + l15) * 8;
    const _Float16* vlane = Vh2 + (size_t)b * (size_t)N_ * C_ + lane*4;

    f32x4 acc[4][2];
    #pragma unroll
    for (int ct = 0; ct < 4; ++ct)
        #pragma unroll
        for (int f = 0; f < 2; ++f) { acc[ct][f][0]=0.f; acc[ct][f][1]=0.f; acc[ct][f][2]=0.f; acc[ct][f][3]=0.f; }
    float m0 = -3e38f, m1 = -3e38f, l0 = 0.f, l1 = 0.f;

    half8  ka[4], kb[4];
    half4v va[4][4], vb[4][4];

    auto pref = [&](half8 (&kf)[4], half4v (&vf)[4][4], int j0) {
        #pragma unroll
        for (int js = 0; js < 4; ++js)
            kf[js] = *(const half8*)(klane + (size_t)(j0 + js*16) * 8);
        const int jc0 = j0 >> 4;
        #pragma unroll
        for (int js = 0; js < 4; ++js)
            #pragma unroll
            for (int ct = 0; ct < 4; ++ct)
                vf[js][ct] = *(const half4v*)(vlane + (size_t)((jc0 + js)*16 + w4 + ct) * 256);
    };

    auto step = [&](const half8 (&kf)[4], const half4v (&vf)[4][4],
                    half8 (&kfn)[4], half4v (&vfn)[4][4], int jnext) {
        // S^T: D[j=quad*4+r][i=l15]
        f32x4 z; z[0]=0.f; z[1]=0.f; z[2]=0.f; z[3]=0.f;
        f32x4 sf0[4], sf1[4];
        #pragma unroll
        for (int js = 0; js < 4; ++js) {
            sf0[js] = __builtin_amdgcn_mfma_f32_16x16x32_f16(kf[js], qf0, z, 0, 0, 0);
            sf1[js] = __builtin_amdgcn_mfma_f32_16x16x32_f16(kf[js], qf1, z, 0, 0, 0);
        }
        if (jnext < N_) pref(kfn, vfn, jnext);   // loads fly under softmax+PV

        half4v pf0[4], pf1[4];
        {   // i-half 0
            float mx = sf0[0][0];
            #pragma unroll
            for (int js = 0; js < 4; ++js)
                #pragma unroll
                for (int r = 0; r < 4; ++r) mx = fmaxf(mx, sf0[js][r]);
            mx = fmaxf(mx, __shfl_xor(mx, 16));
            mx = fmaxf(mx, __shfl_xor(mx, 32));
            const float mn = fmaxf(m0, mx);
            const float al = __expf(m0 - mn);
            m0 = mn;
            float s = 0.f;
            #pragma unroll
            for (int js = 0; js < 4; ++js) {
                float e0 = __expf(sf0[js][0]-mn), e1 = __expf(sf0[js][1]-mn);
                float e2 = __expf(sf0[js][2]-mn), e3 = __expf(sf0[js][3]-mn);
                s += (e0+e1)+(e2+e3);
                half4v p; p[0]=(_Float16)e0; p[1]=(_Float16)e1; p[2]=(_Float16)e2; p[3]=(_Float16)e3;
                pf0[js] = p;
            }
            l0 = l0*al + s;
            #pragma unroll
            for (int ct = 0; ct < 4; ++ct) {
                acc[ct][0][0]*=al; acc[ct][0][1]*=al; acc[ct][0][2]*=al; acc[ct][0][3]*=al;
            }
        }
        {   // i-half 1
            float mx = sf1[0][0];
            #pragma unroll
            for (int js = 0; js < 4; ++js)
                #pragma unroll
                for (int r = 0; r < 4; ++r) mx = fmaxf(mx, sf1[js][r]);
            mx = fmaxf(mx, __shfl_xor(mx, 16));
            mx = fmaxf(mx, __shfl_xor(mx, 32));
            const float mn = fmaxf(m1, mx);
            const float al = __expf(m1 - mn);
            m1 = mn;
            float s = 0.f;
            #pragma unroll
            for (int js = 0; js < 4; ++js) {
                float e0 = __expf(sf1[js][0]-mn), e1 = __expf(sf1[js][1]-mn);
                float e2 = __expf(sf1[js][2]-mn), e3 = __expf(sf1[js][3]-mn);
                s += (e0+e1)+(e2+e3);
                half4v p; p[0]=(_Float16)e0; p[1]=(_Float16)e1; p[2]=(_Float16)e2; p[3]=(_Float16)e3;
                pf1[js] = p;
            }
            l1 = l1*al + s;
            #pragma unroll
            for (int ct = 0; ct < 4; ++ct) {
                acc[ct][1][0]*=al; acc[ct][1][1]*=al; acc[ct][1][2]*=al; acc[ct][1][3]*=al;
            }
        }
        // PV: acc[ct][if] += V_frag(A) * P_frag(B), K=16
        #pragma unroll
        for (int js = 0; js < 4; ++js)
            #pragma unroll
            for (int ct = 0; ct < 4; ++ct) {
                acc[ct][0] = __builtin_amdgcn_mfma_f32_16x16x16f16(vf[js][ct], pf0[js], acc[ct][0], 0, 0, 0);
                acc[ct][1] = __builtin_amdgcn_mfma_f32_16x16x16f16(vf[js][ct], pf1[js], acc[ct][1], 0, 0, 0);
            }
    };

    pref(ka, va, 0);
    #pragma unroll 1
    for (int jb2 = 0; jb2 < 32; ++jb2) {
        const int j0 = jb2 * 128;
        step(ka, va, kb, vb, j0 + 64);
        step(kb, vb, ka, va, j0 + 128);
    }

    // Epilogue: combine l across quads (disjoint j per quad), scale, store.
    l0 += __shfl_xor(l0, 16); l0 += __shfl_xor(l0, 32);
    l1 += __shfl_xor(l1, 16); l1 += __shfl_xor(l1, 32);
    const float g = gma[0];
    const float sc0 = g / l0, sc1 = g / l1;
    #pragma unroll
    for (int ct = 0; ct < 4; ++ct)
        #pragma unroll
        for (int r = 0; r < 4; ++r) {
            const int c = c0 + ct*16 + quad*4 + r;
            const size_t idx0 = ((size_t)(b*C_ + c)) * N_ + i0 + l15;
            out[idx0]      = acc[ct][0][r] * sc0 + sem[idx0];
            out[idx0 + 16] = acc[ct][1][r] * sc1 + sem[idx0 + 16];
        }
}

extern "C" void kernel_launch(void* const* d_in, const int* in_sizes, int n_in,
                              void* d_out, int out_size, void* d_ws, size_t ws_size,
                              hipStream_t stream) {
    const float* sem = (const float*)d_in[0];
    const float* str = (const float*)d_in[1];
    const float* Wq  = (const float*)d_in[2];
    const float* bq  = (const float*)d_in[3];
    const float* Wk  = (const float*)d_in[4];
    const float* bk  = (const float*)d_in[5];
    const float* Wv  = (const float*)d_in[6];
    const float* bv  = (const float*)d_in[7];
    const float* gma = (const float*)d_in[8];
    float* out = (float*)d_out;

    // Workspace (f16): Qh 1MB | Kh 1MB | Vh2 8MB | Wh 160KB
    _Float16* Qh  = (_Float16*)d_ws;
    _Float16* Kh  = Qh + (size_t)B_*N_*D_;
    _Float16* Vh2 = Kh + (size_t)B_*N_*D_;
    _Float16* Wh  = Vh2 + (size_t)B_*C_*N_;

    hipLaunchKernelGGL(wcvt_kernel, dim3(320), dim3(256), 0, stream, Wq, Wk, Wv, Wh);
    hipLaunchKernelGGL(proj_kernel, dim3(B_*(N_/64)*2), dim3(256), 0, stream,
                       sem, str, Wh, bq, bk, bv, Qh, Kh, Vh2);
    hipLaunchKernelGGL(flash_kernel, dim3(B_*(N_/32)), dim3(256), 0, stream,
                       Qh, Kh, Vh2, sem, gma, out);
}

// Round 5
// 198.522 us; speedup vs baseline: 2.0616x; 1.0433x over previous
//
#include <hip/hip_runtime.h>

// Problem constants
#define B_   4
#define C_   256
#define N_   4096   // H*W
#define D_   32     // qk projection dim
#define CP   264    // proj s_x row stride (halves): 256 + 8

typedef _Float16 half8  __attribute__((ext_vector_type(8)));
typedef _Float16 half4v __attribute__((ext_vector_type(4)));
typedef _Float16 half2v __attribute__((ext_vector_type(2)));
typedef float    f32x4  __attribute__((ext_vector_type(4)));

// ---------------------------------------------------------------------------
// Kernel 0: convert W (f32) -> Wh (f16), A-frag layout:
// Wh[((t*8+kc)*16 + row)*32 + kk] = W_t[row][kc*32+kk], t: 0-1 q, 2-3 k, 4-19 v
// ---------------------------------------------------------------------------
__global__ __launch_bounds__(256) void wcvt_kernel(
    const float* __restrict__ Wq, const float* __restrict__ Wk,
    const float* __restrict__ Wv, _Float16* __restrict__ Wh)
{
    const int idx = blockIdx.x * 256 + threadIdx.x;
    const int kk  = idx & 31;
    const int row = (idx >> 5) & 15;
    const int kc  = (idx >> 9) & 7;
    const int t   = idx >> 12;
    const int c   = kc*32 + kk;
    float v;
    if (t < 2)      v = Wq[(t*16 + row)*C_ + c];
    else if (t < 4) v = Wk[((t-2)*16 + row)*C_ + c];
    else            v = Wv[((t-4)*16 + row)*C_ + c];
    Wh[idx] = (_Float16)v;
}

// ---------------------------------------------------------------------------
// Kernel 1: projections. v2: single-barrier full-tile staging.
// X staged once as [n=64][c=256] f16 (rows c-contiguous, +8 pad) so every
// B-frag is ONE ds_read_b128. 1 barrier per block (was 16).
// Outputs: Qh,Kh (B, 4 dchunk, N, 8) f16; Vh2 frag-major for flash:
//   frag F = ((jc>>2)*16 + ctg)*4 + (jc&3), each frag 256 halves
//   (lane' = (jl>>2)*16 + cl, e = jl&3)  -- a flash step's 16 frags are
//   one contiguous 8KB window.
// ---------------------------------------------------------------------------
__global__ __launch_bounds__(256, 2) void proj_kernel(
    const float* __restrict__ sem, const float* __restrict__ str,
    const _Float16* __restrict__ Wh,
    const float* __restrict__ bq, const float* __restrict__ bk,
    const float* __restrict__ bv,
    _Float16* __restrict__ Qh, _Float16* __restrict__ Kh, _Float16* __restrict__ Vh2)
{
    __shared__ __align__(16) _Float16 s_x[64 * CP];   // structural, 33 KB
    __shared__ __align__(16) _Float16 s_s[64 * CP];   // semantic (h==0 only)

    const int bid = blockIdx.x;
    const int h   = bid & 1;
    const int nt6 = (bid >> 1) & 63;
    const int b   = bid >> 7;
    const int n0  = nt6 * 64;
    const int tid = threadIdx.x;
    const int w    = tid >> 6;
    const int lane = tid & 63;
    const int quad = lane >> 4;
    const int l15  = lane & 15;

    const int cnt = (w < 2) ? 3 : 2;
    const int t0  = h*10 + ((w < 2) ? w*3 : 6 + (w-2)*2);
    const bool need_sem = (h == 0);

    f32x4 acc[3][4];
    #pragma unroll
    for (int i = 0; i < 3; ++i)
        #pragma unroll
        for (int j = 0; j < 4; ++j) { acc[i][j][0]=0.f; acc[i][j][1]=0.f; acc[i][j][2]=0.f; acc[i][j][3]=0.f; }

    const size_t xbase = (size_t)b * C_ * N_;

    // ---- stage the whole 64n x 256c tile, then ONE barrier ----
    #pragma unroll
    for (int r = 0; r < 8; ++r) {
        const int slot = r*256 + tid;
        const int nq = slot & 15;        // n-quad (consecutive tid -> coalesced)
        const int cp = slot >> 4;        // c-pair 0..127
        const float* p0 = str + xbase + (size_t)(2*cp) * N_ + n0 + nq*4;
        const float4 a4 = *(const float4*)p0;
        const float4 b4 = *(const float4*)(p0 + N_);
        #pragma unroll
        for (int t = 0; t < 4; ++t) {
            half2v hp; hp[0] = (_Float16)a4[t]; hp[1] = (_Float16)b4[t];
            *(half2v*)(s_x + (nq*4 + t)*CP + 2*cp) = hp;
        }
        if (need_sem) {
            const float* p1 = sem + xbase + (size_t)(2*cp) * N_ + n0 + nq*4;
            const float4 c4 = *(const float4*)p1;
            const float4 d4 = *(const float4*)(p1 + N_);
            #pragma unroll
            for (int t = 0; t < 4; ++t) {
                half2v hp; hp[0] = (_Float16)c4[t]; hp[1] = (_Float16)d4[t];
                *(half2v*)(s_s + (nq*4 + t)*CP + 2*cp) = hp;
            }
        }
    }
    __syncthreads();

    // ---- compute: B-frags are single b128 reads, shared across o-tiles ----
    #pragma unroll 1
    for (int kc = 0; kc < 8; ++kc) {
        half8 bfr[4], sfr[4];
        #pragma unroll
        for (int nt = 0; nt < 4; ++nt)
            bfr[nt] = *(const half8*)(s_x + (nt*16 + l15)*CP + kc*32 + quad*8);
        if (w == 0 && need_sem) {
            #pragma unroll
            for (int nt = 0; nt < 4; ++nt)
                sfr[nt] = *(const half8*)(s_s + (nt*16 + l15)*CP + kc*32 + quad*8);
        }
        #pragma unroll
        for (int mi = 0; mi < 3; ++mi) {
            if (mi >= cnt) break;
            const int t = t0 + mi;
            half8 af = *(const half8*)(Wh + ((size_t)((t*8 + kc)*16 + l15))*32 + quad*8);
            #pragma unroll
            for (int nt = 0; nt < 4; ++nt)
                acc[mi][nt] = __builtin_amdgcn_mfma_f32_16x16x32_f16(
                                  af, (t < 2) ? sfr[nt] : bfr[nt], acc[mi][nt], 0, 0, 0);
        }
    }

    // ---- epilogue: bias, f16 convert, store ----
    #pragma unroll
    for (int mi = 0; mi < 3; ++mi) {
        if (mi >= cnt) break;
        const int t = t0 + mi;
        if (t < 4) {
            const bool isq = (t < 2);
            const int  tt  = isq ? t : (t - 2);
            f32x4 b4 = *(const f32x4*)((isq ? bq : bk) + tt*16 + quad*4);
            _Float16* dst = isq ? Qh : Kh;
            const int dc  = tt*2 + (quad >> 1);
            const int off = (quad & 1) * 4;
            #pragma unroll
            for (int nt = 0; nt < 4; ++nt) {
                const int n = n0 + nt*16 + l15;
                f32x4 a = acc[mi][nt];
                half4v hq;
                hq[0]=(_Float16)(a[0]+b4[0]); hq[1]=(_Float16)(a[1]+b4[1]);
                hq[2]=(_Float16)(a[2]+b4[2]); hq[3]=(_Float16)(a[3]+b4[3]);
                *(half4v*)(dst + ((size_t)(b*4 + dc) * N_ + n) * 8 + off) = hq;
            }
        } else {
            const int ctg = t - 4;                      // global c-tile 0..15
            const int o0  = ctg*16 + quad*4;
            f32x4 b4 = *(const f32x4*)(bv + o0);
            _Float16* vb = Vh2 + (size_t)b * (size_t)N_ * C_;
            #pragma unroll
            for (int nt = 0; nt < 4; ++nt) {
                const int jc = (n0 >> 4) + nt;
                const int F  = ((jc >> 2)*16 + ctg)*4 + (jc & 3);
                const size_t fragb = (size_t)F * 256;
                const int lp = (l15 >> 2) * 16;
                const int e  = l15 & 3;
                f32x4 a = acc[mi][nt];
                #pragma unroll
                for (int r = 0; r < 4; ++r)
                    vb[fragb + (size_t)(lp + quad*4 + r)*4 + e] = (_Float16)(a[r] + b4[r]);
            }
        }
    }
}

// ---------------------------------------------------------------------------
// Kernel 2: flash attention v5 — fixed-max two-phase, zero-LDS main loop.
// Phase 0: 4 waves split j 4-ways, exact row max via S^T MFMA, combine
// through 512 B of LDS (ONE barrier). Main loop: no rescale/max machinery —
// exp(s - max), per-lane l accumulate, register-resident P into 16x16x16 PV.
// ---------------------------------------------------------------------------
__global__ __launch_bounds__(256, 2) void flash_kernel(
    const _Float16* __restrict__ Qh, const _Float16* __restrict__ Kh,
    const _Float16* __restrict__ Vh2, const float* __restrict__ sem,
    const float* __restrict__ gma, float* __restrict__ out)
{
    __shared__ float s_mp[4*32];

    const int bid = blockIdx.x;
    const int b   = bid >> 7;
    const int i0  = (bid & 127) * 32;
    const int tid = threadIdx.x;
    const int w    = tid >> 6;
    const int lane = tid & 63;
    const int quad = lane >> 4;
    const int l15  = lane & 15;
    const int c0   = w * 64;
    const int w4   = w * 4;

    // Q B-frags (persistent): B[k=d][n=i]
    const _Float16* qk_base = Qh + (size_t)(b*4 + quad) * N_ * 8;
    const half8 qf0 = *(const half8*)(qk_base + (size_t)(i0 + l15) * 8);
    const half8 qf1 = *(const half8*)(qk_base + (size_t)(i0 + 16 + l15) * 8);

    const _Float16* klane = Kh + ((size_t)(b*4 + quad) * N_ + l15) * 8;
    const _Float16* vlane = Vh2 + (size_t)b * (size_t)N_ * C_ + lane*4;

    // ---- phase 0: exact row max (wave w covers j in [w*1024, w*1024+1024)) ----
    float mx0 = -3e38f, mx1 = -3e38f;
    #pragma unroll 1
    for (int it = 0; it < 16; ++it) {
        const int j0 = w*1024 + it*64;
        #pragma unroll
        for (int js = 0; js < 4; ++js) {
            half8 kf = *(const half8*)(klane + (size_t)(j0 + js*16) * 8);
            f32x4 z; z[0]=0.f; z[1]=0.f; z[2]=0.f; z[3]=0.f;
            f32x4 s0 = __builtin_amdgcn_mfma_f32_16x16x32_f16(kf, qf0, z, 0, 0, 0);
            f32x4 s1 = __builtin_amdgcn_mfma_f32_16x16x32_f16(kf, qf1, z, 0, 0, 0);
            #pragma unroll
            for (int r = 0; r < 4; ++r) { mx0 = fmaxf(mx0, s0[r]); mx1 = fmaxf(mx1, s1[r]); }
        }
    }
    mx0 = fmaxf(mx0, __shfl_xor(mx0, 16)); mx0 = fmaxf(mx0, __shfl_xor(mx0, 32));
    mx1 = fmaxf(mx1, __shfl_xor(mx1, 16)); mx1 = fmaxf(mx1, __shfl_xor(mx1, 32));
    if (lane < 32) s_mp[w*32 + lane] = (lane < 16) ? mx0 : mx1;
    __syncthreads();
    float mf0 = -3e38f, mf1 = -3e38f;
    #pragma unroll
    for (int ww = 0; ww < 4; ++ww) {
        mf0 = fmaxf(mf0, s_mp[ww*32 + l15]);
        mf1 = fmaxf(mf1, s_mp[ww*32 + 16 + l15]);
    }

    // ---- main loop ----
    f32x4 acc[4][2];
    #pragma unroll
    for (int ct = 0; ct < 4; ++ct)
        #pragma unroll
        for (int f = 0; f < 2; ++f) { acc[ct][f][0]=0.f; acc[ct][f][1]=0.f; acc[ct][f][2]=0.f; acc[ct][f][3]=0.f; }
    float l0 = 0.f, l1 = 0.f;

    half8  ka[4], kb[4];
    half4v va[4][4], vb[4][4];

    auto pref = [&](half8 (&kf)[4], half4v (&vf)[4][4], int j0) {
        #pragma unroll
        for (int js = 0; js < 4; ++js)
            kf[js] = *(const half8*)(klane + (size_t)(j0 + js*16) * 8);
        const _Float16* vw = vlane + (size_t)((j0 >> 6)*64 + w4*4) * 256;   // 16-frag window
        #pragma unroll
        for (int ct = 0; ct < 4; ++ct)
            #pragma unroll
            for (int js = 0; js < 4; ++js)
                vf[js][ct] = *(const half4v*)(vw + (ct*4 + js) * 256);
    };

    auto step = [&](const half8 (&kf)[4], const half4v (&vf)[4][4],
                    half8 (&kfn)[4], half4v (&vfn)[4][4], int jnext) {
        f32x4 z; z[0]=0.f; z[1]=0.f; z[2]=0.f; z[3]=0.f;
        f32x4 sf0[4], sf1[4];
        #pragma unroll
        for (int js = 0; js < 4; ++js) {
            sf0[js] = __builtin_amdgcn_mfma_f32_16x16x32_f16(kf[js], qf0, z, 0, 0, 0);
            sf1[js] = __builtin_amdgcn_mfma_f32_16x16x32_f16(kf[js], qf1, z, 0, 0, 0);
        }
        if (jnext < N_) pref(kfn, vfn, jnext);

        half4v pf0[4], pf1[4];
        #pragma unroll
        for (int js = 0; js < 4; ++js) {
            float e0 = __expf(sf0[js][0]-mf0), e1 = __expf(sf0[js][1]-mf0);
            float e2 = __expf(sf0[js][2]-mf0), e3 = __expf(sf0[js][3]-mf0);
            l0 += (e0+e1)+(e2+e3);
            half4v p; p[0]=(_Float16)e0; p[1]=(_Float16)e1; p[2]=(_Float16)e2; p[3]=(_Float16)e3;
            pf0[js] = p;
            float f0 = __expf(sf1[js][0]-mf1), f1 = __expf(sf1[js][1]-mf1);
            float f2 = __expf(sf1[js][2]-mf1), f3 = __expf(sf1[js][3]-mf1);
            l1 += (f0+f1)+(f2+f3);
            half4v q; q[0]=(_Float16)f0; q[1]=(_Float16)f1; q[2]=(_Float16)f2; q[3]=(_Float16)f3;
            pf1[js] = q;
        }
        #pragma unroll
        for (int js = 0; js < 4; ++js)
            #pragma unroll
            for (int ct = 0; ct < 4; ++ct) {
                acc[ct][0] = __builtin_amdgcn_mfma_f32_16x16x16f16(vf[js][ct], pf0[js], acc[ct][0], 0, 0, 0);
                acc[ct][1] = __builtin_amdgcn_mfma_f32_16x16x16f16(vf[js][ct], pf1[js], acc[ct][1], 0, 0, 0);
            }
    };

    pref(ka, va, 0);
    #pragma unroll 1
    for (int jb2 = 0; jb2 < 32; ++jb2) {
        const int j0 = jb2 * 128;
        step(ka, va, kb, vb, j0 + 64);
        step(kb, vb, ka, va, j0 + 128);
    }

    // ---- epilogue: combine l across quads (disjoint j per quad), store ----
    l0 += __shfl_xor(l0, 16); l0 += __shfl_xor(l0, 32);
    l1 += __shfl_xor(l1, 16); l1 += __shfl_xor(l1, 32);
    const float g = gma[0];
    const float sc0 = g / l0, sc1 = g / l1;
    #pragma unroll
    for (int ct = 0; ct < 4; ++ct)
        #pragma unroll
        for (int r = 0; r < 4; ++r) {
            const int c = c0 + ct*16 + quad*4 + r;
            const size_t idx0 = ((size_t)(b*C_ + c)) * N_ + i0 + l15;
            out[idx0]      = acc[ct][0][r] * sc0 + sem[idx0];
            out[idx0 + 16] = acc[ct][1][r] * sc1 + sem[idx0 + 16];
        }
}

extern "C" void kernel_launch(void* const* d_in, const int* in_sizes, int n_in,
                              void* d_out, int out_size, void* d_ws, size_t ws_size,
                              hipStream_t stream) {
    const float* sem = (const float*)d_in[0];
    const float* str = (const float*)d_in[1];
    const float* Wq  = (const float*)d_in[2];
    const float* bq  = (const float*)d_in[3];
    const float* Wk  = (const float*)d_in[4];
    const float* bk  = (const float*)d_in[5];
    const float* Wv  = (const float*)d_in[6];
    const float* bv  = (const float*)d_in[7];
    const float* gma = (const float*)d_in[8];
    float* out = (float*)d_out;

    // Workspace (f16): Qh 1MB | Kh 1MB | Vh2 8MB | Wh 160KB
    _Float16* Qh  = (_Float16*)d_ws;
    _Float16* Kh  = Qh + (size_t)B_*N_*D_;
    _Float16* Vh2 = Kh + (size_t)B_*N_*D_;
    _Float16* Wh  = Vh2 + (size_t)B_*C_*N_;

    hipLaunchKernelGGL(wcvt_kernel, dim3(320), dim3(256), 0, stream, Wq, Wk, Wv, Wh);
    hipLaunchKernelGGL(proj_kernel, dim3(B_*(N_/64)*2), dim3(256), 0, stream,
                       sem, str, Wh, bq, bk, bv, Qh, Kh, Vh2);
    hipLaunchKernelGGL(flash_kernel, dim3(B_*(N_/32)), dim3(256), 0, stream,
                       Qh, Kh, Vh2, sem, gma, out);
}